// Round 2
// baseline (363.712 us; speedup 1.0000x reference)
//
#include <hip/hip_runtime.h>
#include <hip/hip_fp16.h>

// Tree NN: reps = emb[tokens] (4096 x 128 x 128); 7x: reps = tanh(concat(pairs) @ W_tree^T + b);
// out = root @ W_cls^T + b_cls.
//
// R2 change: occupancy 1 -> 2 blocks/CU (SPB 16->8, grid 256->512, launch_bounds(256,2)).
// R1 counters showed 11.5% occupancy, MfmaUtil 8%, VALU 27%, HBM 7% -- pure latency-bound;
// co-resident second block provides the wave-level overlap (m114: pipes co-schedule).
//
// W_tree lives in registers as MFMA B-fragments (64 frags, ~256 VGPR/lane), staged once per block.
// Activations live in LDS, stored pair-contiguous so concat(left,right) is free.
// fp16 MFMA 16x16x32, fp32 accumulate, fp32 tanh, fp32 classifier.

typedef _Float16 half8 __attribute__((ext_vector_type(8)));
typedef float floatx4 __attribute__((ext_vector_type(4)));

#define STRIDE 264   // 256 + 8 fp16 pad: A-row ds_read_b128 is exactly 8-cycle (conflict-free)
#define SPB 8        // samples per block

__device__ __forceinline__ float fast_tanh(float x) {
  float cx = fminf(15.f, fmaxf(-15.f, x));
  float e = __expf(2.f * cx);
  return 1.f - 2.f / (e + 1.f);
}

// One wave computes NT output n-tiles [NLO, NLO+NT) of one m-tile for one level.
// A-frag layout: A[m=lane&15][k=quad*8+j]; B-frag: B[k=quad*8+j][n=lane&15];
// D: col=lane&15, row=quad*4+reg (verified layouts, learn_hip m89/m91).
template<int NLO, int NT>
__device__ __forceinline__ void level_tiles(
    const _Float16* inb, _Float16* outb, float* rootbuf,
    const half8 (&Wf)[8][8], const float (&bias)[8],
    int mtile, int Mout, bool writeRoot, int l15, int quad)
{
  floatx4 acc[NT];
#pragma unroll
  for (int i = 0; i < NT; ++i) acc[i] = (floatx4){0.f, 0.f, 0.f, 0.f};

  const _Float16* arow = inb + (mtile * 16 + l15) * STRIDE + quad * 8;
#pragma unroll
  for (int ks = 0; ks < 8; ++ks) {           // K = 256 = 8 steps of 32
    half8 a = *(const half8*)(arow + ks * 32);
#pragma unroll
    for (int i = 0; i < NT; ++i)
      acc[i] = __builtin_amdgcn_mfma_f32_16x16x32_f16(a, Wf[NLO + i][ks], acc[i], 0, 0, 0);
  }

  const int mrow = quad * 4;
#pragma unroll
  for (int i = 0; i < NT; ++i) {
    const int col = (NLO + i) * 16 + l15;    // output feature e
    const float b = bias[NLO + i];
#pragma unroll
    for (int r = 0; r < 4; ++r) {
      const int node = mtile * 16 + mrow + r;
      if (node < Mout) {                     // padded rows at deep levels: skip
        float v = fast_tanh(acc[i][r] + b);
        if (writeRoot) {
          rootbuf[col] = v;                  // Mout==1: only node 0 lands here, fp32
        } else {
          // pair-contiguous store: node j -> row j>>1, half j&1 (next level's A-matrix)
          outb[(node >> 1) * STRIDE + (node & 1) * 128 + col] = (_Float16)v;
        }
      }
    }
  }
}

__global__ __launch_bounds__(256, 2)
void tree_kernel(const int* __restrict__ tokens,
                 const float* __restrict__ embedding,
                 const float* __restrict__ W_tree,
                 const float* __restrict__ b_tree,
                 const float* __restrict__ W_cls,
                 const float* __restrict__ b_cls,
                 float* __restrict__ out)
{
  __shared__ _Float16 bufA[64 * STRIDE];   // leaves / even-level outputs (33.8 KB)
  __shared__ _Float16 bufB[32 * STRIDE];   // odd-level outputs (16.9 KB)
  __shared__ float rootbuf[128];

  const int tid  = threadIdx.x;
  const int wid  = tid >> 6;
  const int lane = tid & 63;
  const int l15  = lane & 15;
  const int quad = lane >> 4;

  // ---- stage all of W_tree into registers as B-fragments (once per block) ----
  // B[k][n] = W_tree[e=n][h=k]  (einsum 'bnh,eh->bne' => out = comb @ W^T)
  half8 Wf[8][8];                          // [ntile][kstep]
#pragma unroll
  for (int n = 0; n < 8; ++n) {
    const int e = n * 16 + l15;
#pragma unroll
    for (int ks = 0; ks < 8; ++ks) {
      const int k = ks * 32 + quad * 8;
      const float4* p = (const float4*)(W_tree + e * 256 + k);
      float4 lo = p[0], hi = p[1];
      half8 f;
      f[0] = (_Float16)lo.x; f[1] = (_Float16)lo.y; f[2] = (_Float16)lo.z; f[3] = (_Float16)lo.w;
      f[4] = (_Float16)hi.x; f[5] = (_Float16)hi.y; f[6] = (_Float16)hi.z; f[7] = (_Float16)hi.w;
      Wf[n][ks] = f;
    }
  }
  float bias[8];
#pragma unroll
  for (int n = 0; n < 8; ++n) bias[n] = b_tree[n * 16 + l15];

#pragma unroll 1
  for (int s0 = 0; s0 < SPB; ++s0) {
    const int s = blockIdx.x * SPB + s0;

    // ---- gather: 128 leaves x 128 feats, fp32 -> fp16, pair-contiguous in bufA ----
    {
      const int leaf = tid >> 1;
      const int hh = tid & 1;
      const int tok = tokens[s * 128 + leaf];
      const float4* src = (const float4*)(embedding + (size_t)tok * 128 + hh * 64);
      _Float16* dst = bufA + (leaf >> 1) * STRIDE + (leaf & 1) * 128 + hh * 64;
#pragma unroll
      for (int j = 0; j < 8; ++j) {
        float4 x = src[2 * j];
        float4 y = src[2 * j + 1];
        half8 h;
        h[0] = (_Float16)x.x; h[1] = (_Float16)x.y; h[2] = (_Float16)x.z; h[3] = (_Float16)x.w;
        h[4] = (_Float16)y.x; h[5] = (_Float16)y.y; h[6] = (_Float16)y.z; h[7] = (_Float16)y.w;
        *(half8*)(dst + j * 8) = h;        // ds_write_b128, 16B aligned
      }
    }
    __syncthreads();

    // ---- 7 tree levels ----
    _Float16* inb = bufA;
    _Float16* outb = bufB;
#pragma unroll
    for (int level = 0; level < 7; ++level) {
      const int Mout = 64 >> level;        // 64,32,16,8,4,2,1
      const bool root = (level == 6);
      if (Mout == 64) {
        // 4 m-tiles: wave w owns m-tile w, all 8 n-tiles
        level_tiles<0, 8>(inb, outb, rootbuf, Wf, bias, wid, Mout, false, l15, quad);
      } else if (Mout == 32) {
        // 2 m-tiles: (wave&1) -> m-tile, (wave>>1) -> n-half
        if ((wid >> 1) == 0) level_tiles<0, 4>(inb, outb, rootbuf, Wf, bias, wid & 1, Mout, false, l15, quad);
        else                 level_tiles<4, 4>(inb, outb, rootbuf, Wf, bias, wid & 1, Mout, false, l15, quad);
      } else {
        // 1 m-tile: wave w owns n-tiles {2w, 2w+1} (all waves stay busy)
        if      (wid == 0) level_tiles<0, 2>(inb, outb, rootbuf, Wf, bias, 0, Mout, root, l15, quad);
        else if (wid == 1) level_tiles<2, 2>(inb, outb, rootbuf, Wf, bias, 0, Mout, root, l15, quad);
        else if (wid == 2) level_tiles<4, 2>(inb, outb, rootbuf, Wf, bias, 0, Mout, root, l15, quad);
        else               level_tiles<6, 2>(inb, outb, rootbuf, Wf, bias, 0, Mout, root, l15, quad);
      }
      __syncthreads();
      _Float16* tmp = inb; inb = outb; outb = tmp;
    }

    // ---- classifier: wave 0, fp32, shuffle reduction ----
    if (wid == 0) {
      const float r0 = rootbuf[lane];
      const float r1 = rootbuf[lane + 64];
#pragma unroll
      for (int o = 0; o < 3; ++o) {
        float p = r0 * W_cls[o * 128 + lane] + r1 * W_cls[o * 128 + 64 + lane];
#pragma unroll
        for (int sh = 32; sh > 0; sh >>= 1) p += __shfl_down(p, sh, 64);
        if (lane == 0) out[s * 3 + o] = p + b_cls[o];
      }
    }
    // next gather writes bufA; last reader of bufA was level 7, already behind a barrier.
    // classifier reads rootbuf (next write is 7 barriers away) -> safe without extra sync.
  }
}

extern "C" void kernel_launch(void* const* d_in, const int* in_sizes, int n_in,
                              void* d_out, int out_size, void* d_ws, size_t ws_size,
                              hipStream_t stream) {
  const int*   tokens    = (const int*)d_in[0];
  const float* embedding = (const float*)d_in[1];
  const float* W_tree    = (const float*)d_in[2];
  const float* b_tree    = (const float*)d_in[3];
  const float* W_cls     = (const float*)d_in[4];
  const float* b_cls     = (const float*)d_in[5];
  float* out = (float*)d_out;

  dim3 grid(512), block(256);   // 512 blocks x 8 samples = 4096 trees; 2 blocks/CU
  tree_kernel<<<grid, block, 0, stream>>>(tokens, embedding, W_tree, b_tree, W_cls, b_cls, out);
}

// Round 3
// 182.422 us; speedup vs baseline: 1.9938x; 1.9938x over previous
//
#include <hip/hip_runtime.h>
#include <hip/hip_fp16.h>

// Tree NN: reps = emb[tokens] (4096 x 128 x 128); 7x: reps = tanh(concat(pairs) @ W_tree^T + b);
// out = root @ W_cls^T + b_cls.
//
// R3: fix R2's spill regression. Wave w now permanently owns output n-tiles {2w, 2w+1}
// (features [32w, 32w+32)) at EVERY level and loops over m-tiles. Each wave holds only
// Wf[2][8] = 64 VGPRs of W-fragments (was 256 -> spilled under launch_bounds(256,2):
// WRITE_SIZE 0.12->44,708 KB scratch traffic). Now ~130 VGPR total -> 3 blocks/CU
// (LDS 50 KB x 3 = 150 <= 160 KB), launch_bounds(256,3), grid-stride 768 blocks.
//
// Activations in LDS, pair-contiguous so concat(left,right) is free.
// fp16 MFMA 16x16x32, fp32 accumulate, fp32 tanh, fp32 classifier.

typedef _Float16 half8 __attribute__((ext_vector_type(8)));
typedef float floatx4 __attribute__((ext_vector_type(4)));

#define STRIDE 264   // 256 + 8 fp16 pad: A-row ds_read_b128 conflict-free
#define NSAMP 4096

__device__ __forceinline__ float fast_tanh(float x) {
  float cx = fminf(15.f, fmaxf(-15.f, x));
  float e = __expf(2.f * cx);
  return 1.f - 2.f / (e + 1.f);
}

// One wave computes its 2 n-tiles for MT m-tiles of one level.
// A-frag: A[m=lane&15][k=quad*8+j]; B-frag: B[k=quad*8+j][n=lane&15];
// D: col=lane&15, row=quad*4+reg (verified layouts, learn_hip m89/m91).
template<int MT>
__device__ __forceinline__ void level_run(
    const _Float16* inb, _Float16* outb, float* rootbuf,
    const half8 (&Wf)[2][8], const float (&bias)[2],
    int Mout, bool writeRoot, int nbase, int l15, int quad)
{
  floatx4 acc[MT][2];
#pragma unroll
  for (int m = 0; m < MT; ++m) {
    acc[m][0] = (floatx4){0.f, 0.f, 0.f, 0.f};
    acc[m][1] = (floatx4){0.f, 0.f, 0.f, 0.f};
  }

#pragma unroll
  for (int m = 0; m < MT; ++m) {
    const _Float16* arow = inb + (m * 16 + l15) * STRIDE + quad * 8;
#pragma unroll
    for (int ks = 0; ks < 8; ++ks) {         // K = 256 = 8 steps of 32
      half8 a = *(const half8*)(arow + ks * 32);
      acc[m][0] = __builtin_amdgcn_mfma_f32_16x16x32_f16(a, Wf[0][ks], acc[m][0], 0, 0, 0);
      acc[m][1] = __builtin_amdgcn_mfma_f32_16x16x32_f16(a, Wf[1][ks], acc[m][1], 0, 0, 0);
    }
  }

  const int mrow = quad * 4;
#pragma unroll
  for (int m = 0; m < MT; ++m) {
#pragma unroll
    for (int i = 0; i < 2; ++i) {
      const int col = (nbase + i) * 16 + l15;  // output feature e
      const float b = bias[i];
#pragma unroll
      for (int r = 0; r < 4; ++r) {
        const int node = m * 16 + mrow + r;
        if (node < Mout) {                     // padded rows at deep levels: skip
          float v = fast_tanh(acc[m][i][r] + b);
          if (writeRoot) {
            rootbuf[col] = v;                  // Mout==1: only node 0 lands here, fp32
          } else {
            // pair-contiguous store: node j -> row j>>1, half j&1 (next level's A-matrix)
            outb[(node >> 1) * STRIDE + (node & 1) * 128 + col] = (_Float16)v;
          }
        }
      }
    }
  }
}

__global__ __launch_bounds__(256, 3)
void tree_kernel(const int* __restrict__ tokens,
                 const float* __restrict__ embedding,
                 const float* __restrict__ W_tree,
                 const float* __restrict__ b_tree,
                 const float* __restrict__ W_cls,
                 const float* __restrict__ b_cls,
                 float* __restrict__ out)
{
  __shared__ _Float16 bufA[64 * STRIDE];   // leaves / even-level outputs (33.8 KB)
  __shared__ _Float16 bufB[32 * STRIDE];   // odd-level outputs (16.9 KB)
  __shared__ float rootbuf[128];

  const int tid  = threadIdx.x;
  const int wid  = tid >> 6;
  const int lane = tid & 63;
  const int l15  = lane & 15;
  const int quad = lane >> 4;
  const int nbase = wid * 2;               // this wave's n-tile base (features [32*wid, 32*wid+32))

  // ---- stage this wave's 2 n-tiles of W_tree into registers as B-fragments ----
  // B[k][n] = W_tree[e=n][h=k]  (einsum 'bnh,eh->bne' => out = comb @ W^T)
  half8 Wf[2][8];                          // 64 VGPRs
#pragma unroll
  for (int i = 0; i < 2; ++i) {
    const int e = (nbase + i) * 16 + l15;
#pragma unroll
    for (int ks = 0; ks < 8; ++ks) {
      const int k = ks * 32 + quad * 8;
      const float4* p = (const float4*)(W_tree + e * 256 + k);
      float4 lo = p[0], hi = p[1];
      half8 f;
      f[0] = (_Float16)lo.x; f[1] = (_Float16)lo.y; f[2] = (_Float16)lo.z; f[3] = (_Float16)lo.w;
      f[4] = (_Float16)hi.x; f[5] = (_Float16)hi.y; f[6] = (_Float16)hi.z; f[7] = (_Float16)hi.w;
      Wf[i][ks] = f;
    }
  }
  float bias[2];
#pragma unroll
  for (int i = 0; i < 2; ++i) bias[i] = b_tree[(nbase + i) * 16 + l15];

#pragma unroll 1
  for (int s = blockIdx.x; s < NSAMP; s += gridDim.x) {

    // ---- gather: 128 leaves x 128 feats, fp32 -> fp16, pair-contiguous in bufA ----
    {
      const int leaf = tid >> 1;
      const int hh = tid & 1;
      const int tok = tokens[s * 128 + leaf];
      const float4* src = (const float4*)(embedding + (size_t)tok * 128 + hh * 64);
      _Float16* dst = bufA + (leaf >> 1) * STRIDE + (leaf & 1) * 128 + hh * 64;
#pragma unroll
      for (int j = 0; j < 8; ++j) {
        float4 x = src[2 * j];
        float4 y = src[2 * j + 1];
        half8 h;
        h[0] = (_Float16)x.x; h[1] = (_Float16)x.y; h[2] = (_Float16)x.z; h[3] = (_Float16)x.w;
        h[4] = (_Float16)y.x; h[5] = (_Float16)y.y; h[6] = (_Float16)y.z; h[7] = (_Float16)y.w;
        *(half8*)(dst + j * 8) = h;        // ds_write_b128, 16B aligned
      }
    }
    __syncthreads();

    // ---- 7 tree levels (ping-pong bufA/bufB) ----
    // level: Mout = 64,32,16,8,4,2,1 ; Mtiles = 4,2,1,1,1,1,1
    level_run<4>(bufA, bufB, rootbuf, Wf, bias, 64, false, nbase, l15, quad);
    __syncthreads();
    level_run<2>(bufB, bufA, rootbuf, Wf, bias, 32, false, nbase, l15, quad);
    __syncthreads();
    level_run<1>(bufA, bufB, rootbuf, Wf, bias, 16, false, nbase, l15, quad);
    __syncthreads();
    level_run<1>(bufB, bufA, rootbuf, Wf, bias,  8, false, nbase, l15, quad);
    __syncthreads();
    level_run<1>(bufA, bufB, rootbuf, Wf, bias,  4, false, nbase, l15, quad);
    __syncthreads();
    level_run<1>(bufB, bufA, rootbuf, Wf, bias,  2, false, nbase, l15, quad);
    __syncthreads();
    level_run<1>(bufA, bufB, rootbuf, Wf, bias,  1, true,  nbase, l15, quad);
    __syncthreads();

    // ---- classifier: wave 0, fp32, shuffle reduction ----
    if (wid == 0) {
      const float r0 = rootbuf[lane];
      const float r1 = rootbuf[lane + 64];
#pragma unroll
      for (int o = 0; o < 3; ++o) {
        float p = r0 * W_cls[o * 128 + lane] + r1 * W_cls[o * 128 + 64 + lane];
#pragma unroll
        for (int sh = 32; sh > 0; sh >>= 1) p += __shfl_down(p, sh, 64);
        if (lane == 0) out[s * 3 + o] = p + b_cls[o];
      }
    }
    // next gather writes bufA; last reader of bufA (root level) is behind the final barrier.
    // classifier reads rootbuf, next written 7 barriers later -> safe without extra sync.
  }
}

extern "C" void kernel_launch(void* const* d_in, const int* in_sizes, int n_in,
                              void* d_out, int out_size, void* d_ws, size_t ws_size,
                              hipStream_t stream) {
  const int*   tokens    = (const int*)d_in[0];
  const float* embedding = (const float*)d_in[1];
  const float* W_tree    = (const float*)d_in[2];
  const float* b_tree    = (const float*)d_in[3];
  const float* W_cls     = (const float*)d_in[4];
  const float* b_cls     = (const float*)d_in[5];
  float* out = (float*)d_out;

  dim3 grid(768), block(256);   // 3 blocks/CU x 256 CUs; grid-stride over 4096 samples
  tree_kernel<<<grid, block, 0, stream>>>(tokens, embedding, W_tree, b_tree, W_cls, b_cls, out);
}